// Round 9
// baseline (738.403 us; speedup 1.0000x reference)
//
#include <hip/hip_runtime.h>
#include <math.h>

#define IN_DIM 128
#define OUT_DIM 64
#define NEG_SLOPE 0.01f

// ---------------- fused fc + edge count ----------------
// Blocks with (b&3)==0 && (b>>2)<nGemm run a 64-node GEMM tile (LDS-FREE:
// h rows are read via wave-uniform scalar loads, each row read exactly once
// so LDS staging buys nothing); other blocks grid-stride edges doing the
// count/rank histogram atomics. With zero LDS both block types are
// VGPR-capped only -> atomic waves keep high occupancy and their latency
// hides under the GEMM's VALU work.
__global__ __launch_bounds__(256) void fc_edge_kernel(
    const float* __restrict__ h, const float* __restrict__ W,
    const float* __restrict__ al, const float* __restrict__ ar,
    const int* __restrict__ dst,
    float* __restrict__ z, float* __restrict__ s, float* __restrict__ t,
    int* __restrict__ count, int* __restrict__ rank,
    int N, int E, int nGemm, int nEdge) {
  int b = blockIdx.x;
  int tid = threadIdx.x;
  bool isGemm = ((b & 3) == 0) && ((b >> 2) < nGemm);

  if (!isGemm) {
    int eb = b - min((b + 3) >> 2, nGemm);  // edge-block id, 0..nEdge-1
    int stride = nEdge * 256;
    for (int i = eb * 256 + tid; i < E; i += stride)
      rank[i] = atomicAdd(&count[dst[i]], 1);
    return;
  }

  int lane = tid & 63, wid = tid >> 6;
  int nb = (b >> 2) * 64;
  int n0 = nb + wid * 16;  // this wave's 16 rows

  // clamped row bases (uniform per instruction -> scalar loads; clamp keeps
  // OOB rows reading valid memory, result discarded by guarded epilogue)
  size_t rb[16];
#pragma unroll
  for (int nn = 0; nn < 16; ++nn)
    rb[nn] = (size_t)min(n0 + nn, N - 1) * IN_DIM;

  float acc[16];
#pragma unroll
  for (int i = 0; i < 16; ++i) acc[i] = 0.f;

  for (int kq = 0; kq < IN_DIM / 4; ++kq) {
    int k = kq * 4;
    float w0 = W[(size_t)(k + 0) * OUT_DIM + lane];  // L1-hot, coalesced
    float w1 = W[(size_t)(k + 1) * OUT_DIM + lane];
    float w2 = W[(size_t)(k + 2) * OUT_DIM + lane];
    float w3 = W[(size_t)(k + 3) * OUT_DIM + lane];
#pragma unroll
    for (int nn = 0; nn < 16; ++nn) {
      float4 hv = *(const float4*)&h[rb[nn] + k];  // wave-uniform broadcast
      float a = acc[nn];
      a = fmaf(hv.x, w0, a);
      a = fmaf(hv.y, w1, a);
      a = fmaf(hv.z, w2, a);
      a = fmaf(hv.w, w3, a);
      acc[nn] = a;
    }
  }

  float alv = al[lane], arv = ar[lane];
#pragma unroll
  for (int nn = 0; nn < 16; ++nn) {
    int row = n0 + nn;
    float p = acc[nn] * alv;
    float q = acc[nn] * arv;
#pragma unroll
    for (int off = 32; off; off >>= 1) {
      p += __shfl_down(p, off);
      q += __shfl_down(q, off);
    }
    if (row < N) {
      z[(size_t)row * OUT_DIM + lane] = acc[nn];
      if (lane == 0) { s[row] = p; t[row] = q; }
    }
  }
}

// ---------------- CSR build ----------------
__global__ __launch_bounds__(256) void scan_block_sums(const int* __restrict__ count, int N,
                                                       int* __restrict__ bsums) {
  int b = blockIdx.x, tid = threadIdx.x;
  int base = b * 2048;
  int sum = 0;
  for (int i = tid; i < 2048; i += 256) {
    int idx = base + i;
    if (idx < N) sum += count[idx];
  }
#pragma unroll
  for (int off = 32; off; off >>= 1) sum += __shfl_down(sum, off);
  __shared__ int ws[4];
  int lane = tid & 63, wid = tid >> 6;
  if (lane == 0) ws[wid] = sum;
  __syncthreads();
  if (tid == 0) bsums[b] = ws[0] + ws[1] + ws[2] + ws[3];
}

// scan_write derives its own block offset by redundantly scanning
// bsums (NB <= 256) -- saves a separate scan_bsums kernel launch.
__global__ __launch_bounds__(256) void scan_write(const int* __restrict__ count, int N,
                                                  const int* __restrict__ bsums, int NB,
                                                  int* __restrict__ offs, int E) {
  __shared__ int sb[256];
  __shared__ int wtot4[4];
  int tid = threadIdx.x, lane = tid & 63, wid = tid >> 6;

  int v0 = (tid < NB) ? bsums[tid] : 0;
  int x0 = v0;
#pragma unroll
  for (int off = 1; off < 64; off <<= 1) {
    int y = __shfl_up(x0, off);
    if (lane >= off) x0 += y;
  }
  if (lane == 63) wtot4[wid] = x0;
  __syncthreads();
  int wb = 0;
  for (int w = 0; w < wid; ++w) wb += wtot4[w];
  sb[tid] = x0 - v0 + wb;  // exclusive prefix
  __syncthreads();

  int b = blockIdx.x;
  int bofs = sb[b];
  if (b == 0 && tid == 0) offs[N] = E;
  __syncthreads();

  int base = b * 2048 + tid * 8;
  int v[8];
  int tot = 0;
#pragma unroll
  for (int i = 0; i < 8; ++i) {
    int idx = base + i;
    int c = (idx < N) ? count[idx] : 0;
    v[i] = c;
    tot += c;
  }
  int x = tot;
#pragma unroll
  for (int off = 1; off < 64; off <<= 1) {
    int y = __shfl_up(x, off);
    if (lane >= off) x += y;
  }
  __shared__ int wtot[4];
  if (lane == 63) wtot[wid] = x;
  __syncthreads();
  int wbase = 0;
  for (int w2 = 0; w2 < wid; ++w2) wbase += wtot[w2];
  int run = bofs + wbase + (x - tot);
#pragma unroll
  for (int i = 0; i < 8; ++i) {
    int idx = base + i;
    if (idx < N) offs[idx] = run;
    run += v[i];
  }
}

// ---------------- edge pass 2: scatter src into CSR order (no atomics) ----------------
__global__ void edge_pass2(const int* __restrict__ src, const int* __restrict__ dst,
                           const int* __restrict__ rank, const int* __restrict__ offs,
                           int* __restrict__ csr_src, int E) {
  int i = blockIdx.x * blockDim.x + threadIdx.x;
  if (i >= E) return;
  int d = dst[i];
  csr_src[offs[d] + rank[i]] = src[i];
}

// ---------------- aggregate: wave per node, 4-row float4 gather ----------------
// Softmax phase: lane = edge slot (lane<deg). Gather phase: wave = 4 row
// groups x 16 col-quads; one dwordx4 load covers 4 z-rows (1 KB coalesced).
// The deg<=64 branch is wave-uniform (all 64 lanes active), lanes >= deg
// hold w_l=0, sn_l=0 -> pad the loop to a multiple of 8 instead of a
// masked tail (masked __shfl reads inactive source lanes = undefined).
__global__ __launch_bounds__(256) void aggregate_kernel(
    const int* __restrict__ offs, const int* __restrict__ csr_src,
    const float* __restrict__ s, const float* __restrict__ t,
    const float* __restrict__ z, float* __restrict__ out, int N) {
  int wid = threadIdx.x >> 6, lane = threadIdx.x & 63;
  int n = blockIdx.x * 4 + wid;
  if (n >= N) return;
  int beg = offs[n], end = offs[n + 1];
  int deg = end - beg;

  if (deg > 0 && deg <= 64) {
    float tn = t[n];
    float e_l = -INFINITY;
    int sn_l = 0;
    if (lane < deg) {
      sn_l = csr_src[beg + lane];
      float e = s[sn_l] + tn;
      e_l = e > 0.f ? e : NEG_SLOPE * e;
    }
    float mn = e_l;
#pragma unroll
    for (int off = 32; off; off >>= 1) mn = fmaxf(mn, __shfl_xor(mn, off));
    float w_l = (lane < deg) ? __expf(e_l - mn) : 0.f;
    float wsum = w_l;
#pragma unroll
    for (int off = 32; off; off >>= 1) wsum += __shfl_xor(wsum, off);
    float inv = 1.0f / wsum;

    int g = lane >> 4, c = lane & 15;
    float4 a4 = make_float4(0.f, 0.f, 0.f, 0.f);
    int degR = (deg + 7) & ~7;  // padded: lanes >= deg contribute w=0
    for (int k = 0; k < degR; k += 8) {
      int i1 = k + g, i2 = k + 4 + g;  // always < 64
      int s1 = __shfl(sn_l, i1), s2 = __shfl(sn_l, i2);
      float w1 = __shfl(w_l, i1), w2 = __shfl(w_l, i2);
      float4 v1 = *(const float4*)&z[(size_t)s1 * OUT_DIM + c * 4];
      float4 v2 = *(const float4*)&z[(size_t)s2 * OUT_DIM + c * 4];
      a4.x = fmaf(w1, v1.x, a4.x); a4.y = fmaf(w1, v1.y, a4.y);
      a4.z = fmaf(w1, v1.z, a4.z); a4.w = fmaf(w1, v1.w, a4.w);
      a4.x = fmaf(w2, v2.x, a4.x); a4.y = fmaf(w2, v2.y, a4.y);
      a4.z = fmaf(w2, v2.z, a4.z); a4.w = fmaf(w2, v2.w, a4.w);
    }
#pragma unroll
    for (int off = 16; off <= 32; off <<= 1) {
      a4.x += __shfl_xor(a4.x, off);
      a4.y += __shfl_xor(a4.y, off);
      a4.z += __shfl_xor(a4.z, off);
      a4.w += __shfl_xor(a4.w, off);
    }
    if (lane < 16) {
      a4.x *= inv; a4.y *= inv; a4.z *= inv; a4.w *= inv;
      *(float4*)&out[(size_t)n * OUT_DIM + lane * 4] = a4;
    }
  } else if (deg > 64) {
    float tn = t[n];
    float mn = -INFINITY;
    for (int p = beg + lane; p < end; p += 64) {
      float e = s[csr_src[p]] + tn;
      e = e > 0.f ? e : NEG_SLOPE * e;
      mn = fmaxf(mn, e);
    }
#pragma unroll
    for (int off = 32; off; off >>= 1) mn = fmaxf(mn, __shfl_xor(mn, off));
    float wsum = 0.f;
    float acc = 0.f;
    for (int p = beg; p < end; ++p) {
      int sn = csr_src[p];
      float e = s[sn] + tn;
      e = e > 0.f ? e : NEG_SLOPE * e;
      float w = __expf(e - mn);
      wsum += w;
      acc = fmaf(w, z[(size_t)sn * OUT_DIM + lane], acc);
    }
    out[(size_t)n * OUT_DIM + lane] = acc / wsum;
  } else {
    if (lane < 16)
      *(float4*)&out[(size_t)n * OUT_DIM + lane * 4] = make_float4(0.f, 0.f, 0.f, 0.f);
  }
}

extern "C" void kernel_launch(void* const* d_in, const int* in_sizes, int n_in,
                              void* d_out, int out_size, void* d_ws, size_t ws_size,
                              hipStream_t stream) {
  const float* h = (const float*)d_in[0];
  const int* src = (const int*)d_in[1];
  const int* dst = (const int*)d_in[2];
  const float* W = (const float*)d_in[3];
  const float* al = (const float*)d_in[4];
  const float* ar = (const float*)d_in[5];
  float* out = (float*)d_out;
  int N = in_sizes[0] / IN_DIM;
  int E = in_sizes[1];

  // workspace layout (all written before read every call)
  float* z = (float*)d_ws;                 // N*64
  float* s = z + (size_t)N * OUT_DIM;      // N
  float* t = s + N;                        // N
  int* count = (int*)(t + N);              // N
  int* offs = count + N;                   // N+1
  int* rank = offs + N + 1;                // E
  int* csr_src = rank + E;                 // E
  int* bsums = csr_src + E;                // <=256

  const int NB = (N + 2047) / 2048;
  const int nGemm = (N + 63) / 64;
  const int nEdge = 3 * nGemm;            // 1:3 interleave
  const int nTotal = nGemm + nEdge;

  hipMemsetAsync(count, 0, (size_t)N * sizeof(int), stream);
  hipLaunchKernelGGL(fc_edge_kernel, dim3(nTotal), dim3(256), 0, stream,
                     h, W, al, ar, dst, z, s, t, count, rank, N, E, nGemm, nEdge);
  hipLaunchKernelGGL(scan_block_sums, dim3(NB), dim3(256), 0, stream, count, N, bsums);
  hipLaunchKernelGGL(scan_write, dim3(NB), dim3(256), 0, stream, count, N, bsums, NB, offs, E);
  hipLaunchKernelGGL(edge_pass2, dim3((E + 255) / 256), dim3(256), 0, stream, src, dst, rank, offs, csr_src, E);
  hipLaunchKernelGGL(aggregate_kernel, dim3((N + 3) / 4), dim3(256), 0, stream, offs, csr_src, s, t, z, out, N);
}

// Round 10
// 312.179 us; speedup vs baseline: 2.3653x; 2.3653x over previous
//
#include <hip/hip_runtime.h>
#include <math.h>

#define IN_DIM 128
#define OUT_DIM 64
#define NEG_SLOPE 0.01f

// ---------------- fc: z = h @ W ; s = z@a_l ; t = z@a_r ----------------
// 32 nodes/block, 4 waves, wave=8 nodes, lane=output column.
// h-tile in LDS (16 KiB): staging converts broadcast h reads into
// full-width coalesced loads (round-9 lesson: removing it is 3x slower).
// At 16 KiB the LDS cap (10 blocks/CU) exceeds the wave cap (8) -> occupancy
// is wave-limited. W (32 KB, shared by all blocks) stays L1-hot from global.
__global__ __launch_bounds__(256) void fc_kernel(
    const float* __restrict__ h, const float* __restrict__ W,
    const float* __restrict__ al, const float* __restrict__ ar,
    float* __restrict__ z, float* __restrict__ s, float* __restrict__ t, int N) {
  __shared__ float hlds[32][IN_DIM];  // 16 KiB
  int tid = threadIdx.x;
  int nb = blockIdx.x * 32;

  for (int it = tid; it < 32 * (IN_DIM / 4); it += 256) {
    int r = it >> 5;        // 0..31
    int kq = it & 31;
    int row = nb + r;
    float4 v = make_float4(0.f, 0.f, 0.f, 0.f);
    if (row < N) v = *(const float4*)&h[(size_t)row * IN_DIM + kq * 4];
    *(float4*)&hlds[r][kq * 4] = v;
  }
  __syncthreads();

  int lane = tid & 63, wid = tid >> 6;
  int n0 = wid * 8;  // 8 nodes per wave
  float acc[8];
#pragma unroll
  for (int i = 0; i < 8; ++i) acc[i] = 0.f;

  for (int kq = 0; kq < IN_DIM / 4; ++kq) {
    int k = kq * 4;
    float w0 = W[(size_t)(k + 0) * OUT_DIM + lane];  // L1-hot, coalesced
    float w1 = W[(size_t)(k + 1) * OUT_DIM + lane];
    float w2 = W[(size_t)(k + 2) * OUT_DIM + lane];
    float w3 = W[(size_t)(k + 3) * OUT_DIM + lane];
#pragma unroll
    for (int nn = 0; nn < 8; ++nn) {
      float4 hv = *(const float4*)&hlds[n0 + nn][k];  // LDS broadcast
      float a = acc[nn];
      a = fmaf(hv.x, w0, a);
      a = fmaf(hv.y, w1, a);
      a = fmaf(hv.z, w2, a);
      a = fmaf(hv.w, w3, a);
      acc[nn] = a;
    }
  }

  float alv = al[lane], arv = ar[lane];
#pragma unroll
  for (int nn = 0; nn < 8; ++nn) {
    int row = nb + n0 + nn;
    float p = acc[nn] * alv;
    float q = acc[nn] * arv;
#pragma unroll
    for (int off = 32; off; off >>= 1) {
      p += __shfl_down(p, off);
      q += __shfl_down(q, off);
    }
    if (row < N) {
      z[(size_t)row * OUT_DIM + lane] = acc[nn];
      if (lane == 0) { s[row] = p; t[row] = q; }
    }
  }
}

// ---------------- edge pass 1: degree count + rank, ILP-8 atomics ----------------
// 8 edges per thread: 8 independent atomicAdd returns in flight before the
// rank writes (round-4 version had ~1 in flight -> latency-bound at 69us).
__global__ __launch_bounds__(256) void edge_pass1(const int* __restrict__ dst,
                                                  int* __restrict__ count,
                                                  int* __restrict__ rank, int E) {
  int base = (blockIdx.x * blockDim.x + threadIdx.x) * 8;
  if (base + 8 <= E) {
    int4 d0 = *(const int4*)&dst[base];
    int4 d1 = *(const int4*)&dst[base + 4];
    int r0 = atomicAdd(&count[d0.x], 1);
    int r1 = atomicAdd(&count[d0.y], 1);
    int r2 = atomicAdd(&count[d0.z], 1);
    int r3 = atomicAdd(&count[d0.w], 1);
    int r4 = atomicAdd(&count[d1.x], 1);
    int r5 = atomicAdd(&count[d1.y], 1);
    int r6 = atomicAdd(&count[d1.z], 1);
    int r7 = atomicAdd(&count[d1.w], 1);
    *(int4*)&rank[base] = make_int4(r0, r1, r2, r3);
    *(int4*)&rank[base + 4] = make_int4(r4, r5, r6, r7);
  } else {
    for (int i = base; i < E; ++i) rank[i] = atomicAdd(&count[dst[i]], 1);
  }
}

// ---------------- CSR build ----------------
__global__ __launch_bounds__(256) void scan_block_sums(const int* __restrict__ count, int N,
                                                       int* __restrict__ bsums) {
  int b = blockIdx.x, tid = threadIdx.x;
  int base = b * 2048;
  int sum = 0;
  for (int i = tid; i < 2048; i += 256) {
    int idx = base + i;
    if (idx < N) sum += count[idx];
  }
#pragma unroll
  for (int off = 32; off; off >>= 1) sum += __shfl_down(sum, off);
  __shared__ int ws[4];
  int lane = tid & 63, wid = tid >> 6;
  if (lane == 0) ws[wid] = sum;
  __syncthreads();
  if (tid == 0) bsums[b] = ws[0] + ws[1] + ws[2] + ws[3];
}

// scan_write derives its own block offset by redundantly scanning
// bsums (NB <= 256) -- saves a separate scan_bsums kernel launch.
__global__ __launch_bounds__(256) void scan_write(const int* __restrict__ count, int N,
                                                  const int* __restrict__ bsums, int NB,
                                                  int* __restrict__ offs, int E) {
  __shared__ int sb[256];
  __shared__ int wtot4[4];
  int tid = threadIdx.x, lane = tid & 63, wid = tid >> 6;

  int v0 = (tid < NB) ? bsums[tid] : 0;
  int x0 = v0;
#pragma unroll
  for (int off = 1; off < 64; off <<= 1) {
    int y = __shfl_up(x0, off);
    if (lane >= off) x0 += y;
  }
  if (lane == 63) wtot4[wid] = x0;
  __syncthreads();
  int wb = 0;
  for (int w = 0; w < wid; ++w) wb += wtot4[w];
  sb[tid] = x0 - v0 + wb;  // exclusive prefix
  __syncthreads();

  int b = blockIdx.x;
  int bofs = sb[b];
  if (b == 0 && tid == 0) offs[N] = E;
  __syncthreads();

  int base = b * 2048 + tid * 8;
  int v[8];
  int tot = 0;
#pragma unroll
  for (int i = 0; i < 8; ++i) {
    int idx = base + i;
    int c = (idx < N) ? count[idx] : 0;
    v[i] = c;
    tot += c;
  }
  int x = tot;
#pragma unroll
  for (int off = 1; off < 64; off <<= 1) {
    int y = __shfl_up(x, off);
    if (lane >= off) x += y;
  }
  __shared__ int wtot[4];
  if (lane == 63) wtot[wid] = x;
  __syncthreads();
  int wbase = 0;
  for (int w2 = 0; w2 < wid; ++w2) wbase += wtot[w2];
  int run = bofs + wbase + (x - tot);
#pragma unroll
  for (int i = 0; i < 8; ++i) {
    int idx = base + i;
    if (idx < N) offs[idx] = run;
    run += v[i];
  }
}

// ---------------- edge pass 2: scatter src into CSR order (no atomics) ----------------
__global__ void edge_pass2(const int* __restrict__ src, const int* __restrict__ dst,
                           const int* __restrict__ rank, const int* __restrict__ offs,
                           int* __restrict__ csr_src, int E) {
  int i = blockIdx.x * blockDim.x + threadIdx.x;
  if (i >= E) return;
  int d = dst[i];
  csr_src[offs[d] + rank[i]] = src[i];
}

// ---------------- aggregate: wave per node, 4-row float4 gather ----------------
__global__ __launch_bounds__(256) void aggregate_kernel(
    const int* __restrict__ offs, const int* __restrict__ csr_src,
    const float* __restrict__ s, const float* __restrict__ t,
    const float* __restrict__ z, float* __restrict__ out, int N) {
  int wid = threadIdx.x >> 6, lane = threadIdx.x & 63;
  int n = blockIdx.x * 4 + wid;
  if (n >= N) return;
  int beg = offs[n], end = offs[n + 1];
  int deg = end - beg;

  if (deg > 0 && deg <= 64) {
    float tn = t[n];
    float e_l = -INFINITY;
    int sn_l = 0;
    if (lane < deg) {
      sn_l = csr_src[beg + lane];
      float e = s[sn_l] + tn;
      e_l = e > 0.f ? e : NEG_SLOPE * e;
    }
    float mn = e_l;
#pragma unroll
    for (int off = 32; off; off >>= 1) mn = fmaxf(mn, __shfl_xor(mn, off));
    float w_l = (lane < deg) ? __expf(e_l - mn) : 0.f;
    float wsum = w_l;
#pragma unroll
    for (int off = 32; off; off >>= 1) wsum += __shfl_xor(wsum, off);
    float inv = 1.0f / wsum;

    int g = lane >> 4, c = lane & 15;
    float4 a4 = make_float4(0.f, 0.f, 0.f, 0.f);
    int degR = (deg + 7) & ~7;  // padded: lanes >= deg contribute w=0
    for (int k = 0; k < degR; k += 8) {
      int i1 = k + g, i2 = k + 4 + g;  // always < 64
      int s1 = __shfl(sn_l, i1), s2 = __shfl(sn_l, i2);
      float w1 = __shfl(w_l, i1), w2 = __shfl(w_l, i2);
      float4 v1 = *(const float4*)&z[(size_t)s1 * OUT_DIM + c * 4];
      float4 v2 = *(const float4*)&z[(size_t)s2 * OUT_DIM + c * 4];
      a4.x = fmaf(w1, v1.x, a4.x); a4.y = fmaf(w1, v1.y, a4.y);
      a4.z = fmaf(w1, v1.z, a4.z); a4.w = fmaf(w1, v1.w, a4.w);
      a4.x = fmaf(w2, v2.x, a4.x); a4.y = fmaf(w2, v2.y, a4.y);
      a4.z = fmaf(w2, v2.z, a4.z); a4.w = fmaf(w2, v2.w, a4.w);
    }
#pragma unroll
    for (int off = 16; off <= 32; off <<= 1) {
      a4.x += __shfl_xor(a4.x, off);
      a4.y += __shfl_xor(a4.y, off);
      a4.z += __shfl_xor(a4.z, off);
      a4.w += __shfl_xor(a4.w, off);
    }
    if (lane < 16) {
      a4.x *= inv; a4.y *= inv; a4.z *= inv; a4.w *= inv;
      *(float4*)&out[(size_t)n * OUT_DIM + lane * 4] = a4;
    }
  } else if (deg > 64) {
    float tn = t[n];
    float mn = -INFINITY;
    for (int p = beg + lane; p < end; p += 64) {
      float e = s[csr_src[p]] + tn;
      e = e > 0.f ? e : NEG_SLOPE * e;
      mn = fmaxf(mn, e);
    }
#pragma unroll
    for (int off = 32; off; off >>= 1) mn = fmaxf(mn, __shfl_xor(mn, off));
    float wsum = 0.f;
    float acc = 0.f;
    for (int p = beg; p < end; ++p) {
      int sn = csr_src[p];
      float e = s[sn] + tn;
      e = e > 0.f ? e : NEG_SLOPE * e;
      float w = __expf(e - mn);
      wsum += w;
      acc = fmaf(w, z[(size_t)sn * OUT_DIM + lane], acc);
    }
    out[(size_t)n * OUT_DIM + lane] = acc / wsum;
  } else {
    if (lane < 16)
      *(float4*)&out[(size_t)n * OUT_DIM + lane * 4] = make_float4(0.f, 0.f, 0.f, 0.f);
  }
}

extern "C" void kernel_launch(void* const* d_in, const int* in_sizes, int n_in,
                              void* d_out, int out_size, void* d_ws, size_t ws_size,
                              hipStream_t stream) {
  const float* h = (const float*)d_in[0];
  const int* src = (const int*)d_in[1];
  const int* dst = (const int*)d_in[2];
  const float* W = (const float*)d_in[3];
  const float* al = (const float*)d_in[4];
  const float* ar = (const float*)d_in[5];
  float* out = (float*)d_out;
  int N = in_sizes[0] / IN_DIM;
  int E = in_sizes[1];

  // workspace layout (all written before read every call)
  float* z = (float*)d_ws;                 // N*64
  float* s = z + (size_t)N * OUT_DIM;      // N
  float* t = s + N;                        // N
  int* count = (int*)(t + N);              // N
  int* offs = count + N;                   // N+1
  int* rank = offs + N + 1;                // E
  int* csr_src = rank + E;                 // E
  int* bsums = csr_src + E;                // <=256

  const int NB = (N + 2047) / 2048;

  hipMemsetAsync(count, 0, (size_t)N * sizeof(int), stream);
  hipLaunchKernelGGL(fc_kernel, dim3((N + 31) / 32), dim3(256), 0, stream,
                     h, W, al, ar, z, s, t, N);
  hipLaunchKernelGGL(edge_pass1, dim3((E + 2047) / 2048), dim3(256), 0, stream,
                     dst, count, rank, E);
  hipLaunchKernelGGL(scan_block_sums, dim3(NB), dim3(256), 0, stream, count, N, bsums);
  hipLaunchKernelGGL(scan_write, dim3(NB), dim3(256), 0, stream, count, N, bsums, NB, offs, E);
  hipLaunchKernelGGL(edge_pass2, dim3((E + 255) / 256), dim3(256), 0, stream, src, dst, rank, offs, csr_src, E);
  hipLaunchKernelGGL(aggregate_kernel, dim3((N + 3) / 4), dim3(256), 0, stream, offs, csr_src, s, t, z, out, N);
}

// Round 16
// 267.776 us; speedup vs baseline: 2.7575x; 1.1658x over previous
//
#include <hip/hip_runtime.h>
#include <math.h>

#define IN_DIM 128
#define OUT_DIM 64
#define NEG_SLOPE 0.01f

__device__ __forceinline__ float bf2f(unsigned int u) {
  return __uint_as_float(u << 16);
}
__device__ __forceinline__ unsigned short f2bf(float f) {
  unsigned int u = __float_as_uint(f);
  u += 0x7fffu + ((u >> 16) & 1u);  // round-to-nearest-even
  return (unsigned short)(u >> 16);
}

// ---------------- fused fc + edge histogram ----------------
// b%5==4 -> edge block (ILP-8 count/rank atomics, grid-stride);
// else gemm block: 32 nodes, h-tile in 16 KiB LDS (16KiB*8 blocks = 128KiB
// < 160KiB so LDS never caps occupancy -- round-7 lesson), W read from
// global (L1-hot). The atomic service-rate ceiling (round-10: 23 G/s,
// VALUBusy 0.2%) doesn't consume VALU/HBM, so fc compute overlaps ~free.
__global__ __launch_bounds__(256) void fc_edge_kernel(
    const float* __restrict__ h, const float* __restrict__ W,
    const float* __restrict__ al, const float* __restrict__ ar,
    const int* __restrict__ dst,
    unsigned short* __restrict__ z, float* __restrict__ s, float* __restrict__ t,
    int* __restrict__ count, int* __restrict__ rank,
    int N, int E, int nGemm, int nEdgeBlocks) {
  int b = blockIdx.x;
  int tid = threadIdx.x;

  if (b % 5 == 4) {  // ---- edge role ----
    int eb = b / 5;
    int stride = nEdgeBlocks * 2048;
    for (int base = eb * 2048 + tid * 8; base < E; base += stride) {
      if (base + 8 <= E) {
        int4 d0 = *(const int4*)&dst[base];
        int4 d1 = *(const int4*)&dst[base + 4];
        int r0 = atomicAdd(&count[d0.x], 1);
        int r1 = atomicAdd(&count[d0.y], 1);
        int r2 = atomicAdd(&count[d0.z], 1);
        int r3 = atomicAdd(&count[d0.w], 1);
        int r4 = atomicAdd(&count[d1.x], 1);
        int r5 = atomicAdd(&count[d1.y], 1);
        int r6 = atomicAdd(&count[d1.z], 1);
        int r7 = atomicAdd(&count[d1.w], 1);
        *(int4*)&rank[base] = make_int4(r0, r1, r2, r3);
        *(int4*)&rank[base + 4] = make_int4(r4, r5, r6, r7);
      } else {
        for (int i = base; i < E; ++i) rank[i] = atomicAdd(&count[dst[i]], 1);
      }
    }
    return;
  }

  int gb = b - (b + 1) / 5;  // gemm block id (edge blocks removed)
  if (gb >= nGemm) return;

  __shared__ float hlds[32][IN_DIM];  // 16 KiB
  int nb = gb * 32;

  for (int it = tid; it < 32 * (IN_DIM / 4); it += 256) {
    int r = it >> 5;
    int kq = it & 31;
    int row = nb + r;
    float4 v = make_float4(0.f, 0.f, 0.f, 0.f);
    if (row < N) v = *(const float4*)&h[(size_t)row * IN_DIM + kq * 4];
    *(float4*)&hlds[r][kq * 4] = v;
  }
  __syncthreads();

  int lane = tid & 63, wid = tid >> 6;
  int n0 = wid * 8;
  float acc[8];
#pragma unroll
  for (int i = 0; i < 8; ++i) acc[i] = 0.f;

  for (int kq = 0; kq < IN_DIM / 4; ++kq) {
    int k = kq * 4;
    float w0 = W[(size_t)(k + 0) * OUT_DIM + lane];
    float w1 = W[(size_t)(k + 1) * OUT_DIM + lane];
    float w2 = W[(size_t)(k + 2) * OUT_DIM + lane];
    float w3 = W[(size_t)(k + 3) * OUT_DIM + lane];
#pragma unroll
    for (int nn = 0; nn < 8; ++nn) {
      float4 hv = *(const float4*)&hlds[n0 + nn][k];
      float a = acc[nn];
      a = fmaf(hv.x, w0, a);
      a = fmaf(hv.y, w1, a);
      a = fmaf(hv.z, w2, a);
      a = fmaf(hv.w, w3, a);
      acc[nn] = a;
    }
  }

  float alv = al[lane], arv = ar[lane];
#pragma unroll
  for (int nn = 0; nn < 8; ++nn) {
    int row = nb + n0 + nn;
    float p = acc[nn] * alv;
    float q = acc[nn] * arv;
#pragma unroll
    for (int off = 32; off; off >>= 1) {
      p += __shfl_down(p, off);
      q += __shfl_down(q, off);
    }
    if (row < N) {
      z[(size_t)row * OUT_DIM + lane] = f2bf(acc[nn]);
      if (lane == 0) { s[row] = p; t[row] = q; }
    }
  }
}

// ---------------- CSR build ----------------
__global__ __launch_bounds__(256) void scan_block_sums(const int* __restrict__ count, int N,
                                                       int* __restrict__ bsums) {
  int b = blockIdx.x, tid = threadIdx.x;
  int base = b * 2048;
  int sum = 0;
  for (int i = tid; i < 2048; i += 256) {
    int idx = base + i;
    if (idx < N) sum += count[idx];
  }
#pragma unroll
  for (int off = 32; off; off >>= 1) sum += __shfl_down(sum, off);
  __shared__ int ws[4];
  int lane = tid & 63, wid = tid >> 6;
  if (lane == 0) ws[wid] = sum;
  __syncthreads();
  if (tid == 0) bsums[b] = ws[0] + ws[1] + ws[2] + ws[3];
}

__global__ __launch_bounds__(256) void scan_write(const int* __restrict__ count, int N,
                                                  const int* __restrict__ bsums, int NB,
                                                  int* __restrict__ offs, int E) {
  __shared__ int sb[256];
  __shared__ int wtot4[4];
  int tid = threadIdx.x, lane = tid & 63, wid = tid >> 6;

  int v0 = (tid < NB) ? bsums[tid] : 0;
  int x0 = v0;
#pragma unroll
  for (int off = 1; off < 64; off <<= 1) {
    int y = __shfl_up(x0, off);
    if (lane >= off) x0 += y;
  }
  if (lane == 63) wtot4[wid] = x0;
  __syncthreads();
  int wb = 0;
  for (int w = 0; w < wid; ++w) wb += wtot4[w];
  sb[tid] = x0 - v0 + wb;  // exclusive prefix
  __syncthreads();

  int b = blockIdx.x;
  int bofs = sb[b];
  if (b == 0 && tid == 0) offs[N] = E;
  __syncthreads();

  int base = b * 2048 + tid * 8;
  int v[8];
  int tot = 0;
#pragma unroll
  for (int i = 0; i < 8; ++i) {
    int idx = base + i;
    int c = (idx < N) ? count[idx] : 0;
    v[i] = c;
    tot += c;
  }
  int x = tot;
#pragma unroll
  for (int off = 1; off < 64; off <<= 1) {
    int y = __shfl_up(x, off);
    if (lane >= off) x += y;
  }
  __shared__ int wtot[4];
  if (lane == 63) wtot[wid] = x;
  __syncthreads();
  int wbase = 0;
  for (int w2 = 0; w2 < wid; ++w2) wbase += wtot[w2];
  int run = bofs + wbase + (x - tot);
#pragma unroll
  for (int i = 0; i < 8; ++i) {
    int idx = base + i;
    if (idx < N) offs[idx] = run;
    run += v[i];
  }
}

// ---------------- edge pass 2: scatter src into CSR order ----------------
__global__ void edge_pass2(const int* __restrict__ src, const int* __restrict__ dst,
                           const int* __restrict__ rank, const int* __restrict__ offs,
                           int* __restrict__ csr_src, int E) {
  int i = blockIdx.x * blockDim.x + threadIdx.x;
  if (i >= E) return;
  int d = dst[i];
  csr_src[offs[d] + rank[i]] = src[i];
}

// ---------------- aggregate: wave per node, 4-row bf16 gather ----------------
// Softmax: lane = edge slot. Gather: 4 row-groups x 16 col-quads; uint2 =
// 4 bf16 cols per lane; 8 rows (1 KB logical) per iteration. Padded loop,
// all shuffles wave-uniform with all lanes active (round-5 lesson).
__global__ __launch_bounds__(256) void aggregate_kernel(
    const int* __restrict__ offs, const int* __restrict__ csr_src,
    const float* __restrict__ s, const float* __restrict__ t,
    const unsigned short* __restrict__ z, float* __restrict__ out, int N) {
  int wid = threadIdx.x >> 6, lane = threadIdx.x & 63;
  int n = blockIdx.x * 4 + wid;
  if (n >= N) return;
  int beg = offs[n], end = offs[n + 1];
  int deg = end - beg;

  if (deg > 0 && deg <= 64) {
    float tn = t[n];
    float e_l = -INFINITY;
    int sn_l = 0;
    if (lane < deg) {
      sn_l = csr_src[beg + lane];
      float e = s[sn_l] + tn;
      e_l = e > 0.f ? e : NEG_SLOPE * e;
    }
    float mn = e_l;
#pragma unroll
    for (int off = 32; off; off >>= 1) mn = fmaxf(mn, __shfl_xor(mn, off));
    float w_l = (lane < deg) ? __expf(e_l - mn) : 0.f;
    float wsum = w_l;
#pragma unroll
    for (int off = 32; off; off >>= 1) wsum += __shfl_xor(wsum, off);
    float inv = 1.0f / wsum;

    int g = lane >> 4, c = lane & 15;
    float4 a4 = make_float4(0.f, 0.f, 0.f, 0.f);
    int degR = (deg + 7) & ~7;  // lanes >= deg contribute w=0
    for (int k = 0; k < degR; k += 8) {
      int i1 = k + g, i2 = k + 4 + g;  // always < 64
      int s1 = __shfl(sn_l, i1), s2 = __shfl(sn_l, i2);
      float w1 = __shfl(w_l, i1), w2 = __shfl(w_l, i2);
      uint2 u1 = *(const uint2*)&z[(size_t)s1 * OUT_DIM + c * 4];
      uint2 u2 = *(const uint2*)&z[(size_t)s2 * OUT_DIM + c * 4];
      a4.x = fmaf(w1, bf2f(u1.x & 0xffffu), a4.x);
      a4.y = fmaf(w1, bf2f(u1.x >> 16), a4.y);
      a4.z = fmaf(w1, bf2f(u1.y & 0xffffu), a4.z);
      a4.w = fmaf(w1, bf2f(u1.y >> 16), a4.w);
      a4.x = fmaf(w2, bf2f(u2.x & 0xffffu), a4.x);
      a4.y = fmaf(w2, bf2f(u2.x >> 16), a4.y);
      a4.z = fmaf(w2, bf2f(u2.y & 0xffffu), a4.z);
      a4.w = fmaf(w2, bf2f(u2.y >> 16), a4.w);
    }
#pragma unroll
    for (int off = 16; off <= 32; off <<= 1) {
      a4.x += __shfl_xor(a4.x, off);
      a4.y += __shfl_xor(a4.y, off);
      a4.z += __shfl_xor(a4.z, off);
      a4.w += __shfl_xor(a4.w, off);
    }
    if (lane < 16) {
      a4.x *= inv; a4.y *= inv; a4.z *= inv; a4.w *= inv;
      *(float4*)&out[(size_t)n * OUT_DIM + lane * 4] = a4;
    }
  } else if (deg > 64) {
    float tn = t[n];
    float mn = -INFINITY;
    for (int p = beg + lane; p < end; p += 64) {
      float e = s[csr_src[p]] + tn;
      e = e > 0.f ? e : NEG_SLOPE * e;
      mn = fmaxf(mn, e);
    }
#pragma unroll
    for (int off = 32; off; off >>= 1) mn = fmaxf(mn, __shfl_xor(mn, off));
    float wsum = 0.f;
    float acc = 0.f;
    for (int p = beg; p < end; ++p) {
      int sn = csr_src[p];
      float e = s[sn] + tn;
      e = e > 0.f ? e : NEG_SLOPE * e;
      float w = __expf(e - mn);
      wsum += w;
      acc = fmaf(w, bf2f(z[(size_t)sn * OUT_DIM + lane]), acc);
    }
    out[(size_t)n * OUT_DIM + lane] = acc / wsum;
  } else {
    if (lane < 16)
      *(float4*)&out[(size_t)n * OUT_DIM + lane * 4] = make_float4(0.f, 0.f, 0.f, 0.f);
  }
}

extern "C" void kernel_launch(void* const* d_in, const int* in_sizes, int n_in,
                              void* d_out, int out_size, void* d_ws, size_t ws_size,
                              hipStream_t stream) {
  const float* h = (const float*)d_in[0];
  const int* src = (const int*)d_in[1];
  const int* dst = (const int*)d_in[2];
  const float* W = (const float*)d_in[3];
  const float* al = (const float*)d_in[4];
  const float* ar = (const float*)d_in[5];
  float* out = (float*)d_out;
  int N = in_sizes[0] / IN_DIM;
  int E = in_sizes[1];

  // workspace layout (all written before read every call)
  unsigned short* z = (unsigned short*)d_ws;       // N*64 bf16
  float* s = (float*)(z + (size_t)N * OUT_DIM);    // N
  float* t = s + N;                                // N
  int* count = (int*)(t + N);                      // N
  int* offs = count + N;                           // N+1
  int* rank = offs + N + 1;                        // E
  int* csr_src = rank + E;                         // E
  int* bsums = csr_src + E;                        // <=256

  const int NB = (N + 2047) / 2048;
  const int nGemm = (N + 31) / 32;
  const int total = nGemm + (nGemm + 3) / 4;       // ~4:1 gemm:edge interleave
  const int nEdgeBlocks = (total > 4) ? ((total - 5) / 5 + 1) : 1;

  hipMemsetAsync(count, 0, (size_t)N * sizeof(int), stream);
  hipLaunchKernelGGL(fc_edge_kernel, dim3(total), dim3(256), 0, stream,
                     h, W, al, ar, dst, z, s, t, count, rank, N, E, nGemm, nEdgeBlocks);
  hipLaunchKernelGGL(scan_block_sums, dim3(NB), dim3(256), 0, stream, count, N, bsums);
  hipLaunchKernelGGL(scan_write, dim3(NB), dim3(256), 0, stream, count, N, bsums, NB, offs, E);
  hipLaunchKernelGGL(edge_pass2, dim3((E + 255) / 256), dim3(256), 0, stream, src, dst, rank, offs, csr_src, E);
  hipLaunchKernelGGL(aggregate_kernel, dim3((N + 3) / 4), dim3(256), 0, stream, offs, csr_src, s, t, z, out, N);
}